// Round 4
// baseline (12256.377 us; speedup 1.0000x reference)
//
#include <hip/hip_runtime.h>

#define N_INT 16384
#define NPTS  20480
#define DIMX  3
#define NRES  8
#define NFC   3
#define DD    128
#define Q     8            // points per wave
#define WPW   4            // waves per workgroup
#define TPB   (WPW*64)
#define TILES_PER_DIM (NPTS/Q)   // 2560
#define INT_TILES     (N_INT/Q)  // 2048 -> tiles >= this are boundary-only

// 16 FMAs: one k-octet (xa=k0..k0+3, xb=k0+4..k0+7) against 8 staged W rows
#define JET16(acc, xa, xb, WB) do { \
  acc[0]=fmaf(xa.x,WB[0].x,acc[0]); acc[1]=fmaf(xa.x,WB[0].y,acc[1]); \
  acc[0]=fmaf(xa.y,WB[1].x,acc[0]); acc[1]=fmaf(xa.y,WB[1].y,acc[1]); \
  acc[0]=fmaf(xa.z,WB[2].x,acc[0]); acc[1]=fmaf(xa.z,WB[2].y,acc[1]); \
  acc[0]=fmaf(xa.w,WB[3].x,acc[0]); acc[1]=fmaf(xa.w,WB[3].y,acc[1]); \
  acc[0]=fmaf(xb.x,WB[4].x,acc[0]); acc[1]=fmaf(xb.x,WB[4].y,acc[1]); \
  acc[0]=fmaf(xb.y,WB[5].x,acc[0]); acc[1]=fmaf(xb.y,WB[5].y,acc[1]); \
  acc[0]=fmaf(xb.z,WB[6].x,acc[0]); acc[1]=fmaf(xb.z,WB[6].y,acc[1]); \
  acc[0]=fmaf(xb.w,WB[7].x,acc[0]); acc[1]=fmaf(xb.w,WB[7].y,acc[1]); \
} while(0)

// prefetch 8 consecutive W rows (this lane's 2 output features) into WB
#define PREF(WB, KROW) do { \
  const float* wr_ = WL + (size_t)(KROW)*DD + d0; \
  _Pragma("unroll") \
  for (int j_=0;j_<8;++j_) WB[j_] = *(const float2*)(wr_ + j_*DD); \
} while(0)

// heavy: 3 jets x 8 points against one W octet
#define HALF_HEAVY(KOFF, WB) do { \
  _Pragma("unroll") \
  for (int q_=0;q_<Q;++q_) { \
    const float4 x0a=*(const float4*)&A[(q_*3+0)*DD+(KOFF)]; \
    const float4 x0b=*(const float4*)&A[(q_*3+0)*DD+(KOFF)+4]; \
    const float4 x1a=*(const float4*)&A[(q_*3+1)*DD+(KOFF)]; \
    const float4 x1b=*(const float4*)&A[(q_*3+1)*DD+(KOFF)+4]; \
    const float4 x2a=*(const float4*)&A[(q_*3+2)*DD+(KOFF)]; \
    const float4 x2b=*(const float4*)&A[(q_*3+2)*DD+(KOFF)+4]; \
    JET16(av[q_],  x0a,x0b,WB); \
    JET16(ad1[q_], x1a,x1b,WB); \
    JET16(ad2[q_], x2a,x2b,WB); \
  } \
} while(0)

// light: value jet only
#define HALF_LIGHT(KOFF, WB) do { \
  _Pragma("unroll") \
  for (int q_=0;q_<Q;++q_) { \
    const float4 x0a=*(const float4*)&A[q_*DD+(KOFF)]; \
    const float4 x0b=*(const float4*)&A[q_*DD+(KOFF)+4]; \
    JET16(av[q_], x0a,x0b,WB); \
  } \
} while(0)

__global__ __launch_bounds__(TPB, 3) void pinn_main(
    const float* __restrict__ X,
    const float* __restrict__ w_first,
    const float* __restrict__ b_first,
    const float* __restrict__ W_res,
    const float* __restrict__ b_res,
    const float* __restrict__ W_last,
    const float* __restrict__ b_last,
    const float* __restrict__ lb,
    const float* __restrict__ ub,
    float* __restrict__ Fout,
    float* __restrict__ F2out)
{
    __shared__ float ldsA[WPW][3*Q*DD];   // 4 x 12 KB, wave-private regions
    const int wave = threadIdx.x >> 6;
    const int lane = threadIdx.x & 63;
    const int gw   = blockIdx.x * WPW + wave;
    const int dim  = gw / TILES_PER_DIM;
    const int tile = gw % TILES_PER_DIM;
    const int p0   = tile * Q;
    const int d0   = lane * 2;            // this lane owns features d0, d0+1

    float* A = &ldsA[wave][0];

    const float lo = lb[dim], hi = ub[dim];
    const float sc = 2.0f / (hi - lo);
    const float wf0 = w_first[dim*DD + d0];
    const float wf1 = w_first[dim*DD + d0 + 1];
    const float bf0 = b_first[dim*DD + d0];
    const float bf1 = b_first[dim*DD + d0 + 1];

    const float* Wp0 = W_res + (size_t)dim*(NRES*NFC*DD*DD);
    const float* bp0 = b_res + (size_t)dim*(NRES*NFC*DD);
    const float wl0 = W_last[dim*DD + d0];
    const float wl1 = W_last[dim*DD + d0 + 1];
    const float blv = b_last[dim];

    if (tile < INT_TILES) {
        // ================= interior: full 2nd-order jet =================
        float hv[Q][2], hd[Q][2], hdd[Q][2];
#pragma unroll
        for (int q = 0; q < Q; ++q) {
            float x = X[(p0 + q)*DIMX + dim];
            float t = fmaf(x - lo, sc, -1.0f);
            hv[q][0] = fmaf(t, wf0, bf0);
            hv[q][1] = fmaf(t, wf1, bf1);
            hd[q][0] = sc*wf0;
            hd[q][1] = sc*wf1;
            hdd[q][0] = 0.f; hdd[q][1] = 0.f;
        }

        const float* Wp = Wp0;
        const float* bp = bp0;

#pragma unroll 1
        for (int r = 0; r < NRES; ++r) {
            // stage h jets (layer-0 input)
#pragma unroll
            for (int q = 0; q < Q; ++q) {
                *(float2*)&A[(q*3+0)*DD + d0] = make_float2(hv[q][0],  hv[q][1]);
                *(float2*)&A[(q*3+1)*DD + d0] = make_float2(hd[q][0],  hd[q][1]);
                *(float2*)&A[(q*3+2)*DD + d0] = make_float2(hdd[q][0], hdd[q][1]);
            }

#pragma unroll 1
            for (int l = 0; l < NFC; ++l) {
                float av[Q][2] = {}, ad1[Q][2] = {}, ad2[Q][2] = {};
                const float* WL = Wp;
                float2 wb0[8], wb1[8];
                PREF(wb0, 0);
#pragma unroll 1
                for (int k0 = 0; k0 < DD; k0 += 16) {
                    PREF(wb1, k0+8);
                    HALF_HEAVY(k0, wb0);
                    if (k0 + 16 < DD) PREF(wb0, k0+16);
                    HALF_HEAVY(k0+8, wb1);
                }
                const float bv0 = bp[d0], bv1 = bp[d0+1];
#pragma unroll
                for (int q = 0; q < Q; ++q) { av[q][0] += bv0; av[q][1] += bv1; }

                if (l < NFC-1) {
                    // g = sin(a) jet -> straight to LDS
#pragma unroll
                    for (int q = 0; q < Q; ++q) {
                        float nv[2], nd[2], ndd[2];
#pragma unroll
                        for (int i = 0; i < 2; ++i) {
                            float s = __sinf(av[q][i]);
                            float c = __cosf(av[q][i]);
                            nv[i]  = s;
                            ndd[i] = fmaf(c, ad2[q][i], -s*ad1[q][i]*ad1[q][i]);
                            nd[i]  = c*ad1[q][i];
                        }
                        *(float2*)&A[(q*3+0)*DD + d0] = make_float2(nv[0],  nv[1]);
                        *(float2*)&A[(q*3+1)*DD + d0] = make_float2(nd[0],  nd[1]);
                        *(float2*)&A[(q*3+2)*DD + d0] = make_float2(ndd[0], ndd[1]);
                    }
                } else {
                    // h = sin(a + h) jet (residual), stays in registers
#pragma unroll
                    for (int q = 0; q < Q; ++q) {
#pragma unroll
                        for (int i = 0; i < 2; ++i) {
                            float zu = av[q][i]  + hv[q][i];
                            float z1 = ad1[q][i] + hd[q][i];
                            float z2 = ad2[q][i] + hdd[q][i];
                            float s = __sinf(zu);
                            float c = __cosf(zu);
                            hv[q][i]  = s;
                            hd[q][i]  = c*z1;
                            hdd[q][i] = fmaf(c, z2, -s*z1*z1);
                        }
                    }
                }
                Wp += DD*DD;
                bp += DD;
            }
        }

#pragma unroll
        for (int q = 0; q < Q; ++q) {
            float pv = fmaf(hv[q][0],  wl0, hv[q][1]*wl1);
            float p2 = fmaf(hdd[q][0], wl0, hdd[q][1]*wl1);
#pragma unroll
            for (int off = 32; off > 0; off >>= 1) {
                pv += __shfl_down(pv, off);
                p2 += __shfl_down(p2, off);
            }
            if (lane == 0) {
                Fout[dim*NPTS + p0 + q]  = pv + blv;
                F2out[dim*NPTS + p0 + q] = p2;
            }
        }
    } else {
        // ================= boundary: value only (1/3 work) =================
        float hv[Q][2];
#pragma unroll
        for (int q = 0; q < Q; ++q) {
            float x = X[(p0 + q)*DIMX + dim];
            float t = fmaf(x - lo, sc, -1.0f);
            hv[q][0] = fmaf(t, wf0, bf0);
            hv[q][1] = fmaf(t, wf1, bf1);
        }

        const float* Wp = Wp0;
        const float* bp = bp0;

#pragma unroll 1
        for (int r = 0; r < NRES; ++r) {
#pragma unroll
            for (int q = 0; q < Q; ++q)
                *(float2*)&A[q*DD + d0] = make_float2(hv[q][0], hv[q][1]);

#pragma unroll 1
            for (int l = 0; l < NFC; ++l) {
                float av[Q][2] = {};
                const float* WL = Wp;
                float2 wb0[8], wb1[8];
                PREF(wb0, 0);
#pragma unroll 1
                for (int k0 = 0; k0 < DD; k0 += 16) {
                    PREF(wb1, k0+8);
                    HALF_LIGHT(k0, wb0);
                    if (k0 + 16 < DD) PREF(wb0, k0+16);
                    HALF_LIGHT(k0+8, wb1);
                }
                const float bv0 = bp[d0], bv1 = bp[d0+1];
#pragma unroll
                for (int q = 0; q < Q; ++q) { av[q][0] += bv0; av[q][1] += bv1; }

                if (l < NFC-1) {
#pragma unroll
                    for (int q = 0; q < Q; ++q)
                        *(float2*)&A[q*DD + d0] =
                            make_float2(__sinf(av[q][0]), __sinf(av[q][1]));
                } else {
#pragma unroll
                    for (int q = 0; q < Q; ++q) {
                        hv[q][0] = __sinf(av[q][0] + hv[q][0]);
                        hv[q][1] = __sinf(av[q][1] + hv[q][1]);
                    }
                }
                Wp += DD*DD;
                bp += DD;
            }
        }

#pragma unroll
        for (int q = 0; q < Q; ++q) {
            float pv = fmaf(hv[q][0], wl0, hv[q][1]*wl1);
#pragma unroll
            for (int off = 32; off > 0; off >>= 1)
                pv += __shfl_down(pv, off);
            if (lane == 0)
                Fout[dim*NPTS + p0 + q] = pv + blv;
        }
    }
}

__global__ void pinn_combine(const float* __restrict__ F, const float* __restrict__ F2,
                             const float* __restrict__ rhs, float* __restrict__ out)
{
    int n = blockIdx.x*256 + threadIdx.x;
    if (n >= NPTS) return;
    float f0 = F[n], f1 = F[NPTS+n], f2 = F[2*NPTS+n];
    if (n < N_INT) {
        float lap = F2[n]*f1*f2 + F2[NPTS+n]*f0*f2 + F2[2*NPTS+n]*f0*f1;
        out[n] = -lap - rhs[n];
    } else {
        out[n] = f0*f1*f2 - rhs[n];
    }
}

extern "C" void kernel_launch(void* const* d_in, const int* in_sizes, int n_in,
                              void* d_out, int out_size, void* d_ws, size_t ws_size,
                              hipStream_t stream) {
    const float* X       = (const float*)d_in[0];
    const float* rhs     = (const float*)d_in[1];
    const float* w_first = (const float*)d_in[2];
    const float* b_first = (const float*)d_in[3];
    const float* W_res   = (const float*)d_in[4];
    const float* b_res   = (const float*)d_in[5];
    const float* W_last  = (const float*)d_in[6];
    const float* b_last  = (const float*)d_in[7];
    const float* lbv     = (const float*)d_in[8];
    const float* ubv     = (const float*)d_in[9];
    float* out = (float*)d_out;

    float* F  = (float*)d_ws;            // [3][NPTS]
    float* F2 = F + 3*NPTS;              // [3][NPTS]

    int wgs = DIMX * TILES_PER_DIM / WPW; // 1920
    pinn_main<<<wgs, TPB, 0, stream>>>(X, w_first, b_first, W_res, b_res,
                                       W_last, b_last, lbv, ubv, F, F2);
    pinn_combine<<<(NPTS+255)/256, 256, 0, stream>>>(F, F2, rhs, out);
}

// Round 6
// 1785.685 us; speedup vs baseline: 6.8637x; 6.8637x over previous
//
#include <hip/hip_runtime.h>

#define N_INT 16384
#define NPTS  20480
#define DIMX  3
#define NRES  8
#define NFC   3
#define DD    128
#define Q     8            // points per wave
#define WPW   4            // waves per workgroup
#define TPB   (WPW*64)
#define TILES_PER_DIM (NPTS/Q)   // 2560
#define INT_TILES     (N_INT/Q)  // 2048 -> tiles >= this are boundary-only

// 8 FMAs: one k-quad of A (float4) against 4 W rows, 2 output features
#define FMA4(acc, xx)                          \
    acc[0] = fmaf(xx.x, w0.x, acc[0]);         \
    acc[0] = fmaf(xx.y, w1.x, acc[0]);         \
    acc[0] = fmaf(xx.z, w2.x, acc[0]);         \
    acc[0] = fmaf(xx.w, w3.x, acc[0]);         \
    acc[1] = fmaf(xx.x, w0.y, acc[1]);         \
    acc[1] = fmaf(xx.y, w1.y, acc[1]);         \
    acc[1] = fmaf(xx.z, w2.y, acc[1]);         \
    acc[1] = fmaf(xx.w, w3.y, acc[1]);

__device__ __forceinline__ float rlane(float x, int l) {
    return __int_as_float(__builtin_amdgcn_readlane(__float_as_int(x), l));
}

__global__ __launch_bounds__(TPB, 2) void pinn_main(
    const float* __restrict__ X,
    const float* __restrict__ w_first,
    const float* __restrict__ b_first,
    const float* __restrict__ W_res,
    const float* __restrict__ b_res,
    const float* __restrict__ W_last,
    const float* __restrict__ b_last,
    const float* __restrict__ lb,
    const float* __restrict__ ub,
    float* __restrict__ Fout,
    float* __restrict__ F2out)
{
    __shared__ float ldsA[WPW][2*Q*DD];   // 4 x 8 KB, wave-private; jets v,d1 only
    const int wave = threadIdx.x >> 6;
    const int lane = threadIdx.x & 63;
    const int gw   = blockIdx.x * WPW + wave;
    const int dim  = gw / TILES_PER_DIM;
    const int tile = gw % TILES_PER_DIM;
    const int p0   = tile * Q;
    const int d0   = lane * 2;            // this lane owns features d0, d0+1

    float* A = &ldsA[wave][0];

    const float lo = lb[dim], hi = ub[dim];
    const float sc = 2.0f / (hi - lo);
    const float wf0 = w_first[dim*DD + d0];
    const float wf1 = w_first[dim*DD + d0 + 1];
    const float bf0 = b_first[dim*DD + d0];
    const float bf1 = b_first[dim*DD + d0 + 1];

    const float* Wp0 = W_res + (size_t)dim*(NRES*NFC*DD*DD);
    const float* bp0 = b_res + (size_t)dim*(NRES*NFC*DD);
    const float wl0 = W_last[dim*DD + d0];
    const float wl1 = W_last[dim*DD + d0 + 1];
    const float blv = b_last[dim];

    if (tile < INT_TILES) {
        // ================= interior: full 2nd-order jet =================
        float hv[Q][2], hd[Q][2], hdd[Q][2];
#pragma unroll
        for (int q = 0; q < Q; ++q) {
            float x = X[(p0 + q)*DIMX + dim];
            float t = fmaf(x - lo, sc, -1.0f);
            hv[q][0] = fmaf(t, wf0, bf0);
            hv[q][1] = fmaf(t, wf1, bf1);
            hd[q][0] = sc*wf0;
            hd[q][1] = sc*wf1;
            hdd[q][0] = 0.f; hdd[q][1] = 0.f;
        }

        const float* Wp = Wp0;
        const float* bp = bp0;

#pragma unroll 1
        for (int r = 0; r < NRES; ++r) {
            // current d2-jet stays in registers (readlane-broadcast instead of LDS)
            float cdd[Q][2];
#pragma unroll
            for (int q = 0; q < Q; ++q) { cdd[q][0] = hdd[q][0]; cdd[q][1] = hdd[q][1]; }

            // stage v, d1 jets into this wave's LDS region (layer-0 input)
#pragma unroll
            for (int q = 0; q < Q; ++q) {
                *(float2*)&A[(q*2+0)*DD + d0] = make_float2(hv[q][0], hv[q][1]);
                *(float2*)&A[(q*2+1)*DD + d0] = make_float2(hd[q][0], hd[q][1]);
            }

#pragma unroll 1
            for (int l = 0; l < NFC; ++l) {
                float av[Q][2] = {}, ad1[Q][2] = {}, ad2[Q][2] = {};
                const float* WL = Wp;
#pragma unroll 1
                for (int k0 = 0; k0 < DD; k0 += 4) {
                    const float* wr = WL + k0*DD + d0;
                    const float2 w0 = *(const float2*)(wr);
                    const float2 w1 = *(const float2*)(wr + DD);
                    const float2 w2 = *(const float2*)(wr + 2*DD);
                    const float2 w3 = *(const float2*)(wr + 3*DD);
                    const int ls = k0 >> 1;   // uniform: SGPR lane index
#pragma unroll
                    for (int q = 0; q < Q; ++q) {
                        const float4 x0 = *(const float4*)&A[(q*2+0)*DD + k0];
                        const float4 x1 = *(const float4*)&A[(q*2+1)*DD + k0];
                        // d2-jet broadcast from registers via readlane (VALU pipe)
                        const float a0 = rlane(cdd[q][0], ls);
                        const float a1 = rlane(cdd[q][1], ls);
                        const float a2 = rlane(cdd[q][0], ls + 1);
                        const float a3 = rlane(cdd[q][1], ls + 1);
                        FMA4(av[q],  x0);
                        FMA4(ad1[q], x1);
                        ad2[q][0] = fmaf(a0, w0.x, ad2[q][0]);
                        ad2[q][0] = fmaf(a1, w1.x, ad2[q][0]);
                        ad2[q][0] = fmaf(a2, w2.x, ad2[q][0]);
                        ad2[q][0] = fmaf(a3, w3.x, ad2[q][0]);
                        ad2[q][1] = fmaf(a0, w0.y, ad2[q][1]);
                        ad2[q][1] = fmaf(a1, w1.y, ad2[q][1]);
                        ad2[q][1] = fmaf(a2, w2.y, ad2[q][1]);
                        ad2[q][1] = fmaf(a3, w3.y, ad2[q][1]);
                    }
                }
                // bias (value jet only)
                const float bv0 = bp[d0], bv1 = bp[d0+1];
#pragma unroll
                for (int q = 0; q < Q; ++q) { av[q][0] += bv0; av[q][1] += bv1; }

                if (l < NFC-1) {
                    // g = sin(a) jet: v,d1 -> LDS ; d2 -> registers
#pragma unroll
                    for (int q = 0; q < Q; ++q) {
                        float nv[2], nd[2];
#pragma unroll
                        for (int i = 0; i < 2; ++i) {
                            float s = __sinf(av[q][i]);
                            float c = __cosf(av[q][i]);
                            nv[i]  = s;
                            cdd[q][i] = fmaf(c, ad2[q][i], -s*ad1[q][i]*ad1[q][i]);
                            nd[i]  = c*ad1[q][i];
                        }
                        *(float2*)&A[(q*2+0)*DD + d0] = make_float2(nv[0], nv[1]);
                        *(float2*)&A[(q*2+1)*DD + d0] = make_float2(nd[0], nd[1]);
                    }
                } else {
                    // h = sin(a + h) jet (residual), stays in registers
#pragma unroll
                    for (int q = 0; q < Q; ++q) {
#pragma unroll
                        for (int i = 0; i < 2; ++i) {
                            float zu = av[q][i]  + hv[q][i];
                            float z1 = ad1[q][i] + hd[q][i];
                            float z2 = ad2[q][i] + hdd[q][i];
                            float s = __sinf(zu);
                            float c = __cosf(zu);
                            hv[q][i]  = s;
                            hd[q][i]  = c*z1;
                            hdd[q][i] = fmaf(c, z2, -s*z1*z1);
                        }
                    }
                }
                Wp += DD*DD;
                bp += DD;
            }
        }

#pragma unroll
        for (int q = 0; q < Q; ++q) {
            float pv = fmaf(hv[q][0],  wl0, hv[q][1]*wl1);
            float p2 = fmaf(hdd[q][0], wl0, hdd[q][1]*wl1);
#pragma unroll
            for (int off = 32; off > 0; off >>= 1) {
                pv += __shfl_down(pv, off);
                p2 += __shfl_down(p2, off);
            }
            if (lane == 0) {
                Fout[dim*NPTS + p0 + q]  = pv + blv;
                F2out[dim*NPTS + p0 + q] = p2;
            }
        }
    } else {
        // ================= boundary: value only (1/3 work) =================
        float hv[Q][2];
#pragma unroll
        for (int q = 0; q < Q; ++q) {
            float x = X[(p0 + q)*DIMX + dim];
            float t = fmaf(x - lo, sc, -1.0f);
            hv[q][0] = fmaf(t, wf0, bf0);
            hv[q][1] = fmaf(t, wf1, bf1);
        }

        const float* Wp = Wp0;
        const float* bp = bp0;

#pragma unroll 1
        for (int r = 0; r < NRES; ++r) {
#pragma unroll
            for (int q = 0; q < Q; ++q)
                *(float2*)&A[q*DD + d0] = make_float2(hv[q][0], hv[q][1]);

#pragma unroll 1
            for (int l = 0; l < NFC; ++l) {
                float av[Q][2] = {};
                const float* WL = Wp;
#pragma unroll 1
                for (int k0 = 0; k0 < DD; k0 += 4) {
                    const float* wr = WL + k0*DD + d0;
                    const float2 w0 = *(const float2*)(wr);
                    const float2 w1 = *(const float2*)(wr + DD);
                    const float2 w2 = *(const float2*)(wr + 2*DD);
                    const float2 w3 = *(const float2*)(wr + 3*DD);
#pragma unroll
                    for (int q = 0; q < Q; ++q) {
                        const float4 x0 = *(const float4*)&A[q*DD + k0];
                        FMA4(av[q], x0);
                    }
                }
                const float bv0 = bp[d0], bv1 = bp[d0+1];
#pragma unroll
                for (int q = 0; q < Q; ++q) { av[q][0] += bv0; av[q][1] += bv1; }

                if (l < NFC-1) {
#pragma unroll
                    for (int q = 0; q < Q; ++q)
                        *(float2*)&A[q*DD + d0] =
                            make_float2(__sinf(av[q][0]), __sinf(av[q][1]));
                } else {
#pragma unroll
                    for (int q = 0; q < Q; ++q) {
                        hv[q][0] = __sinf(av[q][0] + hv[q][0]);
                        hv[q][1] = __sinf(av[q][1] + hv[q][1]);
                    }
                }
                Wp += DD*DD;
                bp += DD;
            }
        }

#pragma unroll
        for (int q = 0; q < Q; ++q) {
            float pv = fmaf(hv[q][0], wl0, hv[q][1]*wl1);
#pragma unroll
            for (int off = 32; off > 0; off >>= 1)
                pv += __shfl_down(pv, off);
            if (lane == 0)
                Fout[dim*NPTS + p0 + q] = pv + blv;
        }
    }
}

__global__ void pinn_combine(const float* __restrict__ F, const float* __restrict__ F2,
                             const float* __restrict__ rhs, float* __restrict__ out)
{
    int n = blockIdx.x*256 + threadIdx.x;
    if (n >= NPTS) return;
    float f0 = F[n], f1 = F[NPTS+n], f2 = F[2*NPTS+n];
    if (n < N_INT) {
        float lap = F2[n]*f1*f2 + F2[NPTS+n]*f0*f2 + F2[2*NPTS+n]*f0*f1;
        out[n] = -lap - rhs[n];
    } else {
        out[n] = f0*f1*f2 - rhs[n];
    }
}

extern "C" void kernel_launch(void* const* d_in, const int* in_sizes, int n_in,
                              void* d_out, int out_size, void* d_ws, size_t ws_size,
                              hipStream_t stream) {
    const float* X       = (const float*)d_in[0];
    const float* rhs     = (const float*)d_in[1];
    const float* w_first = (const float*)d_in[2];
    const float* b_first = (const float*)d_in[3];
    const float* W_res   = (const float*)d_in[4];
    const float* b_res   = (const float*)d_in[5];
    const float* W_last  = (const float*)d_in[6];
    const float* b_last  = (const float*)d_in[7];
    const float* lbv     = (const float*)d_in[8];
    const float* ubv     = (const float*)d_in[9];
    float* out = (float*)d_out;

    float* F  = (float*)d_ws;            // [3][NPTS]
    float* F2 = F + 3*NPTS;              // [3][NPTS]

    int wgs = DIMX * TILES_PER_DIM / WPW; // 1920
    pinn_main<<<wgs, TPB, 0, stream>>>(X, w_first, b_first, W_res, b_res,
                                       W_last, b_last, lbv, ubv, F, F2);
    pinn_combine<<<(NPTS+255)/256, 256, 0, stream>>>(F, F2, rhs, out);
}